// Round 3
// baseline (660.446 us; speedup 1.0000x reference)
//
#include <hip/hip_runtime.h>
#include <hip/hip_bf16.h>

// Net_79018808312147 — fused single-kernel version.
// x[D]; W_in[D,D]; b_in[D]; weights[L,D,D]; orders[L,D,D]; biases[L,D];
// gather_idx[L,D] i32; scatter_idx[L+1,D] i32 permutations. out = last layer's
// pre-scatter relu((W*O)@inp + b) [D] f32.
//
// R1/R2 (5 separate launches) both ~560 us = 1.08 TB/s implied -- but Little's
// law says even 1 outstanding float4 wave-load x 16 waves/CU (16 KB in flight)
// covers the 9.2 KB needed for 6.3 TB/s. So the time is NOT load-latency; fuse
// into one kernel (kills 4 launch/drain bubbles) and get one big dispatch that
// rocprof can actually show us counters for.
//
// Grid barrier: software, device-scope atomics. Residency guaranteed:
// 256 blocks x 1024 thr, __launch_bounds__(1024,4) caps VGPR at 128 ->
// 16 waves/CU -> exactly 1 block/CU on 256 CUs. Counters zeroed each launch
// by a captured hipMemsetAsync (graph-safe).

#define DD 4096
#define NB 256      // blocks == CUs
#define NT 1024     // 16 waves/block, one output row per wave
#define NLAYER 4

__device__ __forceinline__ void grid_barrier(int* cnt) {
    __syncthreads();                  // all waves' stores drained (vmcnt) first
    if (threadIdx.x == 0) {
        __threadfence();              // release: write back our block's stores
        __hip_atomic_fetch_add(cnt, 1, __ATOMIC_ACQ_REL, __HIP_MEMORY_SCOPE_AGENT);
        while (__hip_atomic_load(cnt, __ATOMIC_ACQUIRE, __HIP_MEMORY_SCOPE_AGENT) < NB) {}
        __threadfence();              // acquire: invalidate stale L1/L2 lines
    }
    __syncthreads();
}

__global__ __launch_bounds__(NT, 4)
void fused_net(const float* __restrict__ x,
               const float* __restrict__ W_in,
               const float* __restrict__ b_in,
               const float* __restrict__ weights,
               const float* __restrict__ orders,
               const float* __restrict__ biases,
               const int*   __restrict__ gidx,
               const int*   __restrict__ sidx,
               float*       __restrict__ out,
               float*       __restrict__ buf0,
               float*       __restrict__ buf1,
               int*         __restrict__ cnt)
{
    __shared__ float sh[DD];
    const int tid  = threadIdx.x;
    const int lane = tid & 63;
    const int wv   = tid >> 6;                 // 0..15
    const int row  = blockIdx.x * 16 + wv;     // one row per wave

    // ---------- input layer: relu(W_in @ x + b_in), scatter by sidx[0] ------
    for (int j = tid; j < DD; j += NT) sh[j] = x[j];
    __syncthreads();
    {
        const float* Wr = W_in + (size_t)row * DD + lane * 4;
        float a0 = 0.f, a1 = 0.f, a2 = 0.f, a3 = 0.f;
        #pragma unroll
        for (int it = 0; it < 16; ++it) {
            float4 w = *reinterpret_cast<const float4*>(Wr + it * 256);
            float4 v = *reinterpret_cast<const float4*>(sh + it * 256 + lane * 4);
            a0 = fmaf(w.x, v.x, a0); a1 = fmaf(w.y, v.y, a1);
            a2 = fmaf(w.z, v.z, a2); a3 = fmaf(w.w, v.w, a3);
        }
        float acc = (a0 + a1) + (a2 + a3);
        #pragma unroll
        for (int off = 32; off; off >>= 1) acc += __shfl_xor(acc, off, 64);
        if (lane == 0) buf0[sidx[row]] = fmaxf(acc + b_in[row], 0.f);
    }
    grid_barrier(cnt + 0);

    // ---------- masked layers ----------------------------------------------
    float* bufs[2] = { buf0, buf1 };
    #pragma unroll
    for (int l = 0; l < NLAYER; ++l) {
        const float* src = bufs[l & 1];
        const int*   g   = gidx + (size_t)l * DD;
        for (int j = tid; j < DD; j += NT) sh[j] = src[g[j]];
        __syncthreads();

        const float* Wr = weights + (size_t)l * DD * DD + (size_t)row * DD + lane * 4;
        const float* Or = orders  + (size_t)l * DD * DD + (size_t)row * DD + lane * 4;
        float a0 = 0.f, a1 = 0.f, a2 = 0.f, a3 = 0.f;
        #pragma unroll
        for (int it = 0; it < 16; ++it) {
            float4 w = *reinterpret_cast<const float4*>(Wr + it * 256);
            float4 o = *reinterpret_cast<const float4*>(Or + it * 256);
            float4 v = *reinterpret_cast<const float4*>(sh + it * 256 + lane * 4);
            a0 = fmaf(w.x * o.x, v.x, a0);
            a1 = fmaf(w.y * o.y, v.y, a1);
            a2 = fmaf(w.z * o.z, v.z, a2);
            a3 = fmaf(w.w * o.w, v.w, a3);
        }
        float acc = (a0 + a1) + (a2 + a3);
        #pragma unroll
        for (int off = 32; off; off >>= 1) acc += __shfl_xor(acc, off, 64);
        float r = fmaxf(acc + biases[(size_t)l * DD + row], 0.f);

        if (l == NLAYER - 1) {
            if (lane == 0) out[row] = r;       // pre-scatter final output
        } else {
            if (lane == 0) bufs[(l + 1) & 1][sidx[(size_t)(l + 1) * DD + row]] = r;
            grid_barrier(cnt + 1 + l);
        }
    }
}

extern "C" void kernel_launch(void* const* d_in, const int* in_sizes, int n_in,
                              void* d_out, int out_size, void* d_ws, size_t ws_size,
                              hipStream_t stream) {
    const float* x       = (const float*)d_in[0];
    const float* W_in    = (const float*)d_in[1];
    const float* b_in    = (const float*)d_in[2];
    const float* weights = (const float*)d_in[3];
    const float* orders  = (const float*)d_in[4];
    const float* biases  = (const float*)d_in[5];
    const int*   gidx    = (const int*)d_in[6];
    const int*   sidx    = (const int*)d_in[7];
    float*       out     = (float*)d_out;

    int*   cnt  = (int*)d_ws;                          // 16 ints, zeroed below
    float* buf0 = (float*)((char*)d_ws + 256);
    float* buf1 = buf0 + DD;

    hipMemsetAsync(d_ws, 0, 256, stream);              // barrier counters = 0

    fused_net<<<NB, NT, 0, stream>>>(x, W_in, b_in, weights, orders, biases,
                                     gidx, sidx, out, buf0, buf1, cnt);
}